// Round 1
// baseline (1803.031 us; speedup 1.0000x reference)
//
#include <hip/hip_runtime.h>
#include <math.h>

// Model_13486197309850: GCN(+self-loop sym-norm, segment_max) || 2-layer BiLSTM -> MLP head.
// Structure:
//   GCN:  deg/CSR build -> h = x@Wgcn (GEMM) -> per-node gather (no atomics) -> relu -> segmax
//   LSTM: Z0 = x@Wih0^T (one GEMM, both dirs) -> per-(dir,row) recurrence blocks (Whh in VGPRs)
//         Z1b = Y0@Wih1b^T -> bwd recurrence (final h only). Fwd lstm1 needs only t=0 -> in head.
//   head: h1f(t=0) gates + concat + W_seq leaky + concat(x_graph) + W1 relu + W2 + log_softmax.
// All fp32 this round (correctness baseline). ws peak ~160.2 MB with region aliasing.

namespace {

constexpr int kN  = 32768;   // nodes / total sequence rows
constexpr int kB  = 128;     // graphs / batch
constexpr int kL  = 256;     // seq len
constexpr int kF  = 768;     // features
constexpr int kNH = 256;     // gcn hidden
constexpr int kH  = 128;     // lstm hidden
constexpr int kE  = 524288;  // edges

__device__ __forceinline__ float sigf(float x)  { return 1.f / (1.f + __expf(-x)); }
__device__ __forceinline__ float tanh_f(float x){ return 1.f - 2.f / (1.f + __expf(2.f * x)); }

// ---------------- GCN: degree count / scan / CSR fill ----------------

__global__ void count_edges(const int* __restrict__ col, int* __restrict__ cnt) {
  int e = blockIdx.x * 256 + threadIdx.x;
  if (e < kE) atomicAdd(&cnt[col[e]], 1);
}

__global__ void scan_dinv(const int* __restrict__ cnt, int* __restrict__ offs,
                          int* __restrict__ cursor, float* __restrict__ dinv) {
  __shared__ int part[1024];
  int t = threadIdx.x;
  int base = t * 32;
  int loc[32];
  int s = 0;
#pragma unroll
  for (int i = 0; i < 32; i++) { loc[i] = cnt[base + i]; s += loc[i]; }
  part[t] = s;
  __syncthreads();
  for (int d = 1; d < 1024; d <<= 1) {
    int v = part[t];
    int add = (t >= d) ? part[t - d] : 0;
    __syncthreads();
    part[t] = v + add;
    __syncthreads();
  }
  int run = (t == 0) ? 0 : part[t - 1];
#pragma unroll
  for (int i = 0; i < 32; i++) {
    offs[base + i] = run;
    cursor[base + i] = run;
    dinv[base + i] = rsqrtf((float)(loc[i] + 1));  // +1 self loop; deg >= 1 always
    run += loc[i];
  }
  if (t == 1023) offs[kN] = run;
}

__global__ void fill_csr(const int* __restrict__ row, const int* __restrict__ col,
                         int* __restrict__ cursor, int* __restrict__ elist) {
  int e = blockIdx.x * 256 + threadIdx.x;
  if (e < kE) {
    int c = col[e];
    int p = atomicAdd(&cursor[c], 1);
    elist[p] = row[e];
  }
}

// ---------------- fp32 tiled GEMM ----------------
// C(M,N) = A(M,K) @ B.  TRANSB ? B stored (N,K) row-major : (K,N) row-major.
// Requires M%128==0, N%64==0, K%16==0 (true for all call sites).
template <bool TRANSB>
__global__ __launch_bounds__(256) void sgemm(const float* __restrict__ A,
                                             const float* __restrict__ B,
                                             float* __restrict__ C,
                                             int M, int N, int K) {
  __shared__ __align__(16) float As[16][132];  // [k][m], +4 pad
  __shared__ __align__(16) float Bs[16][68];   // [k][n], +4 pad
  int tid = threadIdx.x;
  int m0 = blockIdx.y * 128;
  int n0 = blockIdx.x * 64;
  int tx = tid & 15;   // col group (4 cols)
  int ty = tid >> 4;   // row group (rows ty*4..+3 and +64)
  float acc[8][4];
#pragma unroll
  for (int i = 0; i < 8; i++)
#pragma unroll
    for (int j = 0; j < 4; j++) acc[i][j] = 0.f;

  for (int k0 = 0; k0 < K; k0 += 16) {
#pragma unroll
    for (int h = 0; h < 2; h++) {               // A tile: 128x16 = 512 float4
      int f = tid + h * 256;
      int r = f >> 2, cq = f & 3;
      const float4 a = *(const float4*)(A + (size_t)(m0 + r) * K + k0 + cq * 4);
      As[cq * 4 + 0][r] = a.x; As[cq * 4 + 1][r] = a.y;
      As[cq * 4 + 2][r] = a.z; As[cq * 4 + 3][r] = a.w;
    }
    if (TRANSB) {                                // B tile from (N,K): 64 rows x 16 k
      int nn = tid >> 2, kq = tid & 3;
      const float4 bv = *(const float4*)(B + (size_t)(n0 + nn) * K + k0 + kq * 4);
      Bs[kq * 4 + 0][nn] = bv.x; Bs[kq * 4 + 1][nn] = bv.y;
      Bs[kq * 4 + 2][nn] = bv.z; Bs[kq * 4 + 3][nn] = bv.w;
    } else {                                     // B tile from (K,N): 16 k x 64 n
      int kk = tid >> 4, nq = tid & 15;
      const float4 bv = *(const float4*)(B + (size_t)(k0 + kk) * N + n0 + nq * 4);
      *(float4*)&Bs[kk][nq * 4] = bv;
    }
    __syncthreads();
#pragma unroll
    for (int kk = 0; kk < 16; kk++) {
      float4 a0 = *(const float4*)&As[kk][ty * 4];
      float4 a1 = *(const float4*)&As[kk][ty * 4 + 64];
      float4 bq = *(const float4*)&Bs[kk][tx * 4];
      float av[8] = {a0.x, a0.y, a0.z, a0.w, a1.x, a1.y, a1.z, a1.w};
      float bv[4] = {bq.x, bq.y, bq.z, bq.w};
#pragma unroll
      for (int i = 0; i < 8; i++)
#pragma unroll
        for (int j = 0; j < 4; j++) acc[i][j] = fmaf(av[i], bv[j], acc[i][j]);
    }
    __syncthreads();
  }
#pragma unroll
  for (int i = 0; i < 4; i++) {
    *(float4*)(C + (size_t)(m0 + ty * 4 + i) * N + n0 + tx * 4) =
        make_float4(acc[i][0], acc[i][1], acc[i][2], acc[i][3]);
    *(float4*)(C + (size_t)(m0 + 64 + ty * 4 + i) * N + n0 + tx * 4) =
        make_float4(acc[4 + i][0], acc[4 + i][1], acc[4 + i][2], acc[4 + i][3]);
  }
}

// ---------------- GCN gather + relu(+bias), then segment max ----------------

__global__ __launch_bounds__(256) void gcn_gather(const float* __restrict__ hg,
                                                  const int* __restrict__ offs,
                                                  const int* __restrict__ elist,
                                                  const float* __restrict__ dinv,
                                                  const float* __restrict__ bgcn,
                                                  float* __restrict__ out) {
  int n = blockIdx.x, j = threadIdx.x;
  float di = dinv[n];
  float acc = hg[(size_t)n * kNH + j] * (di * di);  // self loop
  int s = offs[n], e = offs[n + 1];
  int p = s;
  for (; p + 4 <= e; p += 4) {
    int r0 = elist[p], r1 = elist[p + 1], r2 = elist[p + 2], r3 = elist[p + 3];
    float w0 = di * dinv[r0], w1 = di * dinv[r1], w2 = di * dinv[r2], w3 = di * dinv[r3];
    float v0 = hg[(size_t)r0 * kNH + j], v1 = hg[(size_t)r1 * kNH + j];
    float v2 = hg[(size_t)r2 * kNH + j], v3 = hg[(size_t)r3 * kNH + j];
    acc = fmaf(v0, w0, acc); acc = fmaf(v1, w1, acc);
    acc = fmaf(v2, w2, acc); acc = fmaf(v3, w3, acc);
  }
  for (; p < e; p++) {
    int r = elist[p];
    acc = fmaf(hg[(size_t)r * kNH + j], di * dinv[r], acc);
  }
  acc += bgcn[j];
  out[(size_t)n * kNH + j] = fmaxf(acc, 0.f);
}

__global__ __launch_bounds__(256) void segmax(const float* __restrict__ xg_full,
                                              float* __restrict__ x_graph) {
  int g = blockIdx.x, j = threadIdx.x;
  const float* base = xg_full + (size_t)g * kL * kNH + j;
  float m0 = -1e30f, m1 = -1e30f, m2 = -1e30f, m3 = -1e30f;
  for (int t = 0; t < kL; t += 4) {
    m0 = fmaxf(m0, base[(size_t)(t + 0) * kNH]);
    m1 = fmaxf(m1, base[(size_t)(t + 1) * kNH]);
    m2 = fmaxf(m2, base[(size_t)(t + 2) * kNH]);
    m3 = fmaxf(m3, base[(size_t)(t + 3) * kNH]);
  }
  x_graph[g * kNH + j] = fmaxf(fmaxf(m0, m1), fmaxf(m2, m3));
}

// ---------------- LSTM recurrence ----------------
// One block per (dir,row). 512 threads; thread g owns gate row g with Whh[g,:] in VGPRs.
// mode 0 (lstm0): grid 256, dir = bx>>7, Z stride 1024 (col off dir*512), per-step store
//                 into Y0 cols dir*128.. ; reverse for dir==1.
// mode 1 (lstm1 bwd): grid 128, dir=1 (weights/bias offset by 512*.), Z stride 512,
//                 reverse scan, store only final h into hfin.
__global__ __launch_bounds__(512, 2) void lstm_rec(const float* __restrict__ Z, int zstride,
                                                   const float* __restrict__ Whh2,
                                                   const float* __restrict__ bias2,
                                                   float* __restrict__ Y0,
                                                   float* __restrict__ hfin, int mode) {
  __shared__ __align__(16) float hbuf[kH];
  __shared__ float gbuf[512];
  int b, dir;
  if (mode == 0) { dir = blockIdx.x >> 7; b = blockIdx.x & 127; }
  else           { dir = 1;               b = blockIdx.x; }
  const bool rev = (dir == 1);
  int g = threadIdx.x;  // 0..511 gate row

  const float* wrow = Whh2 + (size_t)dir * 512 * kH + (size_t)g * kH;
  float w[kH];
#pragma unroll
  for (int k = 0; k < kH / 4; k++) {
    float4 v = *(const float4*)(wrow + 4 * k);
    w[4 * k + 0] = v.x; w[4 * k + 1] = v.y; w[4 * k + 2] = v.z; w[4 * k + 3] = v.w;
  }
  float bg = bias2[dir * 512 + g];
  int zcol = (mode == 0) ? dir * 512 : 0;

  if (g < kH) hbuf[g] = 0.f;
  float c = 0.f;
  __syncthreads();

  const float* zp = Z + (size_t)(b * kL + (rev ? kL - 1 : 0)) * zstride + zcol + g;
  long zinc = rev ? -(long)zstride : (long)zstride;
  float zt = *zp;

  for (int t = 0; t < kL; t++) {
    int tt = rev ? (kL - 1 - t) : t;
    float znext = 0.f;
    if (t < kL - 1) znext = zp[zinc];  // prefetch next row (overlaps the dot)
    zp += zinc;

    float acc = zt + bg;
#pragma unroll
    for (int kk = 0; kk < kH / 4; kk++) {
      float4 h4 = *(const float4*)&hbuf[kk * 4];  // wave-uniform broadcast read
      acc = fmaf(w[4 * kk + 0], h4.x, acc);
      acc = fmaf(w[4 * kk + 1], h4.y, acc);
      acc = fmaf(w[4 * kk + 2], h4.z, acc);
      acc = fmaf(w[4 * kk + 3], h4.w, acc);
    }
    float a = (g < 256 || g >= 384) ? sigf(acc) : tanh_f(acc);  // i,f,o sigmoid; g tanh
    gbuf[g] = a;
    __syncthreads();
    if (g < kH) {
      float ig = gbuf[g], fg = gbuf[kH + g], gg = gbuf[2 * kH + g], og = gbuf[3 * kH + g];
      c = fg * c + ig * gg;
      float hn = og * tanh_f(c);
      hbuf[g] = hn;
      if (mode == 0) Y0[(size_t)(b * kL + tt) * kNH + dir * kH + g] = hn;
    }
    __syncthreads();
    zt = znext;
  }
  if (mode == 1 && g < kH) hfin[b * kH + g] = hbuf[g];
}

// ---------------- head: lstm1-fwd t=0, W_seq, concat, W1, W2, log_softmax ----------------

__global__ __launch_bounds__(256) void head(const float* __restrict__ Y0,
                                            const float* __restrict__ h1b,
                                            const float* __restrict__ Wih1f,
                                            const float* __restrict__ b1f,
                                            const float* __restrict__ xgraph,
                                            const float* __restrict__ Wseq,
                                            const float* __restrict__ bseq,
                                            const float* __restrict__ W1,
                                            const float* __restrict__ b1,
                                            const float* __restrict__ W2,
                                            const float* __restrict__ b2,
                                            float* __restrict__ out) {
  int b = blockIdx.x, t = threadIdx.x;
  __shared__ __align__(16) float x0[kNH];
  __shared__ float gl[512];
  __shared__ __align__(16) float seq[kNH];
  __shared__ __align__(16) float v[512];
  __shared__ __align__(16) float o1[kNH];
  __shared__ float red[512];

  x0[t] = Y0[(size_t)(b * kL) * kNH + t];         // lstm0 output at t=0
  if (t >= kH) seq[t] = h1b[b * kH + (t - kH)];   // bwd final h -> seq[128..255]
  __syncthreads();

  // lstm1 fwd t=0 gate pre-activations (h=0 so no Whh term)
#pragma unroll
  for (int half = 0; half < 2; half++) {
    int g = t + half * 256;
    const float* wr = Wih1f + (size_t)g * kNH;
    float acc = b1f[g];
#pragma unroll 8
    for (int k = 0; k < kNH; k += 4) {
      float4 xv = *(const float4*)&x0[k];
      float4 wv = *(const float4*)(wr + k);
      acc = fmaf(xv.x, wv.x, acc); acc = fmaf(xv.y, wv.y, acc);
      acc = fmaf(xv.z, wv.z, acc); acc = fmaf(xv.w, wv.w, acc);
    }
    gl[g] = acc;
  }
  __syncthreads();
  if (t < kH) {
    float ig = sigf(gl[t]);
    float gg = tanh_f(gl[2 * kH + t]);
    float og = sigf(gl[3 * kH + t]);
    float c = ig * gg;                  // c_init = 0 so forget term vanishes
    seq[t] = og * tanh_f(c);
  }
  v[t] = xgraph[b * kNH + t];
  __syncthreads();

  // x_seq = leaky_relu(seq @ W_seq + b_seq)
  {
    float acc = bseq[t];
#pragma unroll 4
    for (int k = 0; k < kNH; k++) acc = fmaf(seq[k], Wseq[(size_t)k * kNH + t], acc);
    v[kNH + t] = (acc > 0.f) ? acc : 0.01f * acc;
  }
  __syncthreads();

  // out1 = relu([x_graph, x_seq] @ W1 + b1)
  {
    float acc = b1[t];
#pragma unroll 4
    for (int k = 0; k < 512; k++) acc = fmaf(v[k], W1[(size_t)k * kNH + t], acc);
    o1[t] = fmaxf(acc, 0.f);
  }
  __syncthreads();

  // logits + log_softmax
  red[t]        = o1[t] * W2[t * 2 + 0];
  red[kNH + t]  = o1[t] * W2[t * 2 + 1];
  __syncthreads();
  for (int s = 128; s > 0; s >>= 1) {
    if (t < s) { red[t] += red[t + s]; red[kNH + t] += red[kNH + t + s]; }
    __syncthreads();
  }
  if (t == 0) {
    float z0 = red[0] + b2[0], z1 = red[kNH] + b2[1];
    float m = fmaxf(z0, z1);
    float lse = m + logf(__expf(z0 - m) + __expf(z1 - m));
    out[b * 2 + 0] = z0 - lse;
    out[b * 2 + 1] = z1 - lse;
  }
}

}  // namespace

extern "C" void kernel_launch(void* const* d_in, const int* in_sizes, int n_in,
                              void* d_out, int out_size, void* d_ws, size_t ws_size,
                              hipStream_t stream) {
  const float* x     = (const float*)d_in[0];
  const int*   ei    = (const int*)d_in[1];
  // d_in[2] batch == repeat(arange(128), 256) by construction; node n -> graph n/256.
  const float* Wgcn  = (const float*)d_in[3];
  const float* bgcn  = (const float*)d_in[4];
  const float* l0Wih = (const float*)d_in[5];   // (2,512,768) == (1024,768) contiguous
  const float* l0Whh = (const float*)d_in[6];   // (2,512,128)
  const float* l0b   = (const float*)d_in[7];   // (2,512)
  const float* l1Wih = (const float*)d_in[8];   // (2,512,256)
  const float* l1Whh = (const float*)d_in[9];   // (2,512,128)
  const float* l1b   = (const float*)d_in[10];  // (2,512)
  const float* Wseq  = (const float*)d_in[11];
  const float* bseq  = (const float*)d_in[12];
  const float* W1    = (const float*)d_in[13];
  const float* b1    = (const float*)d_in[14];
  const float* W2    = (const float*)d_in[15];
  const float* b2    = (const float*)d_in[16];
  float* out = (float*)d_out;
  char* ws = (char*)d_ws;

  // ws layout (region aliasing; single stream serializes GCN -> LSTM):
  //   [0,128MB)       Z0 (lstm0 gate preacts), later Z1b (first 64MB)
  //                   GCN scratch aliases inside: hgcn@0(32MB), xgfull@32MB(32MB),
  //                   cnt@64MB, offs@65MB, cursor@66MB, elist@67MB(2MB), dinv@70MB
  //   [128MB,160MB)   Y0 (lstm0 bidir outputs, 32768x256 f32)
  //   [160MB,...)     xgraph (128KB), h1b (64KB)
  float* Z0     = (float*)(ws);
  float* Y0     = (float*)(ws + 134217728UL);
  float* xgraph = (float*)(ws + 134217728UL + 33554432UL);
  float* h1b    = (float*)(ws + 134217728UL + 33554432UL + 131072UL);
  float* hgcn   = Z0;
  float* xgfull = (float*)(ws + 33554432UL);
  int*   cnt    = (int*)(ws + 67108864UL);
  int*   offs   = (int*)(ws + 67108864UL + 1048576UL);
  int*   cursor = (int*)(ws + 67108864UL + 2097152UL);
  int*   elist  = (int*)(ws + 67108864UL + 3145728UL);
  float* dinv   = (float*)(ws + 67108864UL + 6291456UL);
  float* Z1b    = Z0;

  const int* erow = ei;        // edge_index[0]
  const int* ecol = ei + kE;   // edge_index[1]

  // ---- GCN path ----
  hipMemsetAsync(cnt, 0, kN * sizeof(int), stream);
  count_edges<<<kE / 256, 256, 0, stream>>>(ecol, cnt);
  scan_dinv<<<1, 1024, 0, stream>>>(cnt, offs, cursor, dinv);
  fill_csr<<<kE / 256, 256, 0, stream>>>(erow, ecol, cursor, elist);
  sgemm<false><<<dim3(kNH / 64, kN / 128), 256, 0, stream>>>(x, Wgcn, hgcn, kN, kNH, kF);
  gcn_gather<<<kN, 256, 0, stream>>>(hgcn, offs, elist, dinv, bgcn, xgfull);
  segmax<<<kB, 256, 0, stream>>>(xgfull, xgraph);

  // ---- LSTM path ----
  sgemm<true><<<dim3(1024 / 64, kN / 128), 256, 0, stream>>>(x, l0Wih, Z0, kN, 1024, kF);
  lstm_rec<<<256, 512, 0, stream>>>(Z0, 1024, l0Whh, l0b, Y0, nullptr, 0);
  sgemm<true><<<dim3(512 / 64, kN / 128), 256, 0, stream>>>(Y0, l1Wih + 512 * 256, Z1b,
                                                            kN, 512, kNH);
  lstm_rec<<<128, 512, 0, stream>>>(Z1b, 512, l1Whh, l1b, nullptr, h1b, 1);

  // ---- head ----
  head<<<kB, 256, 0, stream>>>(Y0, h1b, l1Wih, l1b, xgraph, Wseq, bseq, W1, b1, W2, b2, out);
}

// Round 2
// 1125.257 us; speedup vs baseline: 1.6023x; 1.6023x over previous
//
#include <hip/hip_runtime.h>
#include <math.h>

// Model_13486197309850: GCN(+self-loop sym-norm, segment_max) || 2-layer BiLSTM -> MLP head.
// R1: all big GEMMs -> bf16 MFMA with hi/lo split (3-term, fp32-grade accuracy).
//   A (x / Y0) read as fp32, converted to hi/lo bf16 in-kernel during LDS staging
//   (same bytes as fp32, no extra ws). B (weights) pre-converted to (N,K) bf16 hi/lo,
//   staged via global_load_lds in MFMA fragment-subtile order (linear LDS dest).
// ws peak unchanged from r0 (~168 MB) via region aliasing.

namespace {

constexpr int kN  = 32768;
constexpr int kB  = 128;
constexpr int kL  = 256;
constexpr int kF  = 768;
constexpr int kNH = 256;
constexpr int kH  = 128;
constexpr int kE  = 524288;

typedef __attribute__((ext_vector_type(8))) short bf16x8;
typedef __attribute__((ext_vector_type(4))) float f32x4;
typedef __attribute__((address_space(3))) unsigned int lds_u32;
typedef __attribute__((address_space(1))) unsigned int glb_u32;

__device__ __forceinline__ float sigf(float x)  { return 1.f / (1.f + __expf(-x)); }
__device__ __forceinline__ float tanh_f(float x){ return 1.f - 2.f / (1.f + __expf(2.f * x)); }

__device__ __forceinline__ unsigned short f2bf(float f) {
  unsigned int u = __float_as_uint(f);
  u = u + 0x7fffu + ((u >> 16) & 1u);   // RNE to bf16
  return (unsigned short)(u >> 16);
}
__device__ __forceinline__ float bf2f(unsigned short h) {
  return __uint_as_float((unsigned int)h << 16);
}

// ---------------- GCN: degree count / scan / CSR fill ----------------

__global__ void count_edges(const int* __restrict__ col, int* __restrict__ cnt) {
  int e = blockIdx.x * 256 + threadIdx.x;
  if (e < kE) atomicAdd(&cnt[col[e]], 1);
}

__global__ void scan_dinv(const int* __restrict__ cnt, int* __restrict__ offs,
                          int* __restrict__ cursor, float* __restrict__ dinv) {
  __shared__ int part[1024];
  int t = threadIdx.x;
  int base = t * 32;
  int loc[32];
  int s = 0;
#pragma unroll
  for (int i = 0; i < 32; i++) { loc[i] = cnt[base + i]; s += loc[i]; }
  part[t] = s;
  __syncthreads();
  for (int d = 1; d < 1024; d <<= 1) {
    int v = part[t];
    int add = (t >= d) ? part[t - d] : 0;
    __syncthreads();
    part[t] = v + add;
    __syncthreads();
  }
  int run = (t == 0) ? 0 : part[t - 1];
#pragma unroll
  for (int i = 0; i < 32; i++) {
    offs[base + i] = run;
    cursor[base + i] = run;
    dinv[base + i] = rsqrtf((float)(loc[i] + 1));
    run += loc[i];
  }
  if (t == 1023) offs[kN] = run;
}

__global__ void fill_csr(const int* __restrict__ row, const int* __restrict__ col,
                         int* __restrict__ cursor, int* __restrict__ elist) {
  int e = blockIdx.x * 256 + threadIdx.x;
  if (e < kE) {
    int c = col[e];
    int p = atomicAdd(&cursor[c], 1);
    elist[p] = row[e];
  }
}

// ---------------- weight conversion: fp32 -> (N,K) bf16 hi/lo ----------------
// trans==1: W stored (K,N) row-major, output transposed to (N,K). Else W is (N,K).

__global__ void convert_bt(const float* __restrict__ W, unsigned short* __restrict__ hi,
                           unsigned short* __restrict__ lo, int Nn, int Kk, int trans) {
  int idx = blockIdx.x * 256 + threadIdx.x;
  if (idx >= Nn * Kk) return;
  int n = idx / Kk, k = idx - n * Kk;
  float f = trans ? W[(size_t)k * Nn + n] : W[idx];
  unsigned short h = f2bf(f);
  hi[idx] = h;
  lo[idx] = f2bf(f - bf2f(h));
}

// ---------------- MFMA GEMM, 3-term hi/lo split ----------------
// C(M,N) fp32 = A(M,K) fp32 @ B, with B given as BT hi/lo bf16 (N,K) row-major.
// Tile 128x128, BK=32, 256 threads (4 waves, each 64x64 via 4x4 16x16x32 frags).
// LDS fragment-subtile layout: subtile = 16 rows x 32 k, lane l <-> bytes l*16
// (row l&15, k-group l>>4). A: staged via reg (fp32->hi/lo convert); B: global_load_lds.
__global__ __launch_bounds__(256, 2) void gemm3(const float* __restrict__ A,
                                                const unsigned short* __restrict__ Bhi,
                                                const unsigned short* __restrict__ Blo,
                                                float* __restrict__ C,
                                                int M, int N, int K) {
  __shared__ __align__(16) char lds[32768];  // [0,8K) Ahi, [8K,16K) Alo, [16K,24K) Bhi, [24K,32K) Blo
  const int tid = threadIdx.x;
  const int lane = tid & 63;
  const int w = tid >> 6, wr = w >> 1, wc = w & 1;
  const int m0 = blockIdx.y * 128, n0 = blockIdx.x * 128;

  f32x4 acc[4][4];
#pragma unroll
  for (int i = 0; i < 4; i++)
#pragma unroll
    for (int j = 0; j < 4; j++) acc[i][j] = (f32x4)0.f;

  // A staging: 1024 float4 per K-step (128 rows x 8 quad-k) / 256 thr = 4 each
  const float* aptr[4];
  int aoff[4];
#pragma unroll
  for (int i = 0; i < 4; i++) {
    int f = tid + i * 256;
    int row = f >> 3, kq4 = f & 7;
    aptr[i] = A + (size_t)(m0 + row) * K + kq4 * 4;
    int sub = row >> 4, r = row & 15, q = kq4 >> 1, hs = kq4 & 1;
    aoff[i] = sub * 1024 + (q * 16 + r) * 16 + hs * 8;
  }
  // B staging: 16 subtiles (8 hi + 8 lo) via global_load_lds, 4 issues per wave
  const unsigned short* bsrc[4];
  int boff[4];
#pragma unroll
  for (int j = 0; j < 4; j++) {
    int id = w * 4 + j;
    int isLo = id >> 3, sub = id & 7;
    const unsigned short* Bp = isLo ? Blo : Bhi;
    bsrc[j] = Bp + (size_t)(n0 + sub * 16 + (lane & 15)) * K + (lane >> 4) * 8;
    boff[j] = 16384 + isLo * 8192 + sub * 1024;
  }

  for (int k0 = 0; k0 < K; k0 += 32) {
#pragma unroll
    for (int j = 0; j < 4; j++) {
      __builtin_amdgcn_global_load_lds((const glb_u32*)bsrc[j],
                                       (lds_u32*)(lds + boff[j]), 16, 0, 0);
      bsrc[j] += 32;
    }
#pragma unroll
    for (int i = 0; i < 4; i++) {
      f32x4 v = *(const f32x4*)(aptr[i]);
      aptr[i] += 32;
      unsigned short h0 = f2bf(v.x), h1 = f2bf(v.y), h2 = f2bf(v.z), h3 = f2bf(v.w);
      unsigned short g0 = f2bf(v.x - bf2f(h0)), g1 = f2bf(v.y - bf2f(h1));
      unsigned short g2 = f2bf(v.z - bf2f(h2)), g3 = f2bf(v.w - bf2f(h3));
      uint2 hv, lv;
      hv.x = (unsigned int)h0 | ((unsigned int)h1 << 16);
      hv.y = (unsigned int)h2 | ((unsigned int)h3 << 16);
      lv.x = (unsigned int)g0 | ((unsigned int)g1 << 16);
      lv.y = (unsigned int)g2 | ((unsigned int)g3 << 16);
      *(uint2*)(lds + aoff[i]) = hv;
      *(uint2*)(lds + aoff[i] + 8192) = lv;
    }
    __syncthreads();

    const bf16x8* L = (const bf16x8*)lds;
    bf16x8 ah[4], al[4], bh[4], bl[4];
#pragma unroll
    for (int m = 0; m < 4; m++) {
      ah[m] = L[(wr * 4 + m) * 64 + lane];
      al[m] = L[512 + (wr * 4 + m) * 64 + lane];
    }
#pragma unroll
    for (int n = 0; n < 4; n++) {
      bh[n] = L[1024 + (wc * 4 + n) * 64 + lane];
      bl[n] = L[1536 + (wc * 4 + n) * 64 + lane];
    }
#pragma unroll
    for (int m = 0; m < 4; m++)
#pragma unroll
      for (int n = 0; n < 4; n++) {
        acc[m][n] = __builtin_amdgcn_mfma_f32_16x16x32_bf16(ah[m], bh[n], acc[m][n], 0, 0, 0);
        acc[m][n] = __builtin_amdgcn_mfma_f32_16x16x32_bf16(ah[m], bl[n], acc[m][n], 0, 0, 0);
        acc[m][n] = __builtin_amdgcn_mfma_f32_16x16x32_bf16(al[m], bh[n], acc[m][n], 0, 0, 0);
      }
    __syncthreads();
  }

  // C/D layout: col = lane&15, row = (lane>>4)*4 + reg  [m89-verified]
#pragma unroll
  for (int m = 0; m < 4; m++)
#pragma unroll
    for (int n = 0; n < 4; n++) {
      int r0 = m0 + wr * 64 + m * 16 + (lane >> 4) * 4;
      int cc = n0 + wc * 64 + n * 16 + (lane & 15);
#pragma unroll
      for (int j = 0; j < 4; j++)
        C[(size_t)(r0 + j) * N + cc] = acc[m][n][j];
    }
}

// ---------------- GCN gather + relu(+bias), then segment max ----------------

__global__ __launch_bounds__(256) void gcn_gather(const float* __restrict__ hg,
                                                  const int* __restrict__ offs,
                                                  const int* __restrict__ elist,
                                                  const float* __restrict__ dinv,
                                                  const float* __restrict__ bgcn,
                                                  float* __restrict__ out) {
  int n = blockIdx.x, j = threadIdx.x;
  float di = dinv[n];
  float acc = hg[(size_t)n * kNH + j] * (di * di);
  int s = offs[n], e = offs[n + 1];
  int p = s;
  for (; p + 4 <= e; p += 4) {
    int r0 = elist[p], r1 = elist[p + 1], r2 = elist[p + 2], r3 = elist[p + 3];
    float w0 = di * dinv[r0], w1 = di * dinv[r1], w2 = di * dinv[r2], w3 = di * dinv[r3];
    float v0 = hg[(size_t)r0 * kNH + j], v1 = hg[(size_t)r1 * kNH + j];
    float v2 = hg[(size_t)r2 * kNH + j], v3 = hg[(size_t)r3 * kNH + j];
    acc = fmaf(v0, w0, acc); acc = fmaf(v1, w1, acc);
    acc = fmaf(v2, w2, acc); acc = fmaf(v3, w3, acc);
  }
  for (; p < e; p++) {
    int r = elist[p];
    acc = fmaf(hg[(size_t)r * kNH + j], di * dinv[r], acc);
  }
  acc += bgcn[j];
  out[(size_t)n * kNH + j] = fmaxf(acc, 0.f);
}

__global__ __launch_bounds__(256) void segmax(const float* __restrict__ xg_full,
                                              float* __restrict__ x_graph) {
  int g = blockIdx.x, j = threadIdx.x;
  const float* base = xg_full + (size_t)g * kL * kNH + j;
  float m0 = -1e30f, m1 = -1e30f, m2 = -1e30f, m3 = -1e30f;
  for (int t = 0; t < kL; t += 4) {
    m0 = fmaxf(m0, base[(size_t)(t + 0) * kNH]);
    m1 = fmaxf(m1, base[(size_t)(t + 1) * kNH]);
    m2 = fmaxf(m2, base[(size_t)(t + 2) * kNH]);
    m3 = fmaxf(m3, base[(size_t)(t + 3) * kNH]);
  }
  x_graph[g * kNH + j] = fmaxf(fmaxf(m0, m1), fmaxf(m2, m3));
}

// ---------------- LSTM recurrence (unchanged from r0) ----------------

__global__ __launch_bounds__(512, 2) void lstm_rec(const float* __restrict__ Z, int zstride,
                                                   const float* __restrict__ Whh2,
                                                   const float* __restrict__ bias2,
                                                   float* __restrict__ Y0,
                                                   float* __restrict__ hfin, int mode) {
  __shared__ __align__(16) float hbuf[kH];
  __shared__ float gbuf[512];
  int b, dir;
  if (mode == 0) { dir = blockIdx.x >> 7; b = blockIdx.x & 127; }
  else           { dir = 1;               b = blockIdx.x; }
  const bool rev = (dir == 1);
  int g = threadIdx.x;

  const float* wrow = Whh2 + (size_t)dir * 512 * kH + (size_t)g * kH;
  float w[kH];
#pragma unroll
  for (int k = 0; k < kH / 4; k++) {
    float4 v = *(const float4*)(wrow + 4 * k);
    w[4 * k + 0] = v.x; w[4 * k + 1] = v.y; w[4 * k + 2] = v.z; w[4 * k + 3] = v.w;
  }
  float bg = bias2[dir * 512 + g];
  int zcol = (mode == 0) ? dir * 512 : 0;

  if (g < kH) hbuf[g] = 0.f;
  float c = 0.f;
  __syncthreads();

  const float* zp = Z + (size_t)(b * kL + (rev ? kL - 1 : 0)) * zstride + zcol + g;
  long zinc = rev ? -(long)zstride : (long)zstride;
  float zt = *zp;

  for (int t = 0; t < kL; t++) {
    int tt = rev ? (kL - 1 - t) : t;
    float znext = 0.f;
    if (t < kL - 1) znext = zp[zinc];
    zp += zinc;

    float acc = zt + bg;
#pragma unroll
    for (int kk = 0; kk < kH / 4; kk++) {
      float4 h4 = *(const float4*)&hbuf[kk * 4];
      acc = fmaf(w[4 * kk + 0], h4.x, acc);
      acc = fmaf(w[4 * kk + 1], h4.y, acc);
      acc = fmaf(w[4 * kk + 2], h4.z, acc);
      acc = fmaf(w[4 * kk + 3], h4.w, acc);
    }
    float a = (g < 256 || g >= 384) ? sigf(acc) : tanh_f(acc);
    gbuf[g] = a;
    __syncthreads();
    if (g < kH) {
      float ig = gbuf[g], fg = gbuf[kH + g], gg = gbuf[2 * kH + g], og = gbuf[3 * kH + g];
      c = fg * c + ig * gg;
      float hn = og * tanh_f(c);
      hbuf[g] = hn;
      if (mode == 0) Y0[(size_t)(b * kL + tt) * kNH + dir * kH + g] = hn;
    }
    __syncthreads();
    zt = znext;
  }
  if (mode == 1 && g < kH) hfin[b * kH + g] = hbuf[g];
}

// ---------------- head (unchanged from r0) ----------------

__global__ __launch_bounds__(256) void head(const float* __restrict__ Y0,
                                            const float* __restrict__ h1b,
                                            const float* __restrict__ Wih1f,
                                            const float* __restrict__ b1f,
                                            const float* __restrict__ xgraph,
                                            const float* __restrict__ Wseq,
                                            const float* __restrict__ bseq,
                                            const float* __restrict__ W1,
                                            const float* __restrict__ b1,
                                            const float* __restrict__ W2,
                                            const float* __restrict__ b2,
                                            float* __restrict__ out) {
  int b = blockIdx.x, t = threadIdx.x;
  __shared__ __align__(16) float x0[kNH];
  __shared__ float gl[512];
  __shared__ __align__(16) float seq[kNH];
  __shared__ __align__(16) float v[512];
  __shared__ __align__(16) float o1[kNH];
  __shared__ float red[512];

  x0[t] = Y0[(size_t)(b * kL) * kNH + t];
  if (t >= kH) seq[t] = h1b[b * kH + (t - kH)];
  __syncthreads();

#pragma unroll
  for (int half = 0; half < 2; half++) {
    int g = t + half * 256;
    const float* wr = Wih1f + (size_t)g * kNH;
    float acc = b1f[g];
#pragma unroll 8
    for (int k = 0; k < kNH; k += 4) {
      float4 xv = *(const float4*)&x0[k];
      float4 wv = *(const float4*)(wr + k);
      acc = fmaf(xv.x, wv.x, acc); acc = fmaf(xv.y, wv.y, acc);
      acc = fmaf(xv.z, wv.z, acc); acc = fmaf(xv.w, wv.w, acc);
    }
    gl[g] = acc;
  }
  __syncthreads();
  if (t < kH) {
    float ig = sigf(gl[t]);
    float gg = tanh_f(gl[2 * kH + t]);
    float og = sigf(gl[3 * kH + t]);
    float c = ig * gg;
    seq[t] = og * tanh_f(c);
  }
  v[t] = xgraph[b * kNH + t];
  __syncthreads();

  {
    float acc = bseq[t];
#pragma unroll 4
    for (int k = 0; k < kNH; k++) acc = fmaf(seq[k], Wseq[(size_t)k * kNH + t], acc);
    v[kNH + t] = (acc > 0.f) ? acc : 0.01f * acc;
  }
  __syncthreads();

  {
    float acc = b1[t];
#pragma unroll 4
    for (int k = 0; k < 512; k++) acc = fmaf(v[k], W1[(size_t)k * kNH + t], acc);
    o1[t] = fmaxf(acc, 0.f);
  }
  __syncthreads();

  red[t]       = o1[t] * W2[t * 2 + 0];
  red[kNH + t] = o1[t] * W2[t * 2 + 1];
  __syncthreads();
  for (int s = 128; s > 0; s >>= 1) {
    if (t < s) { red[t] += red[t + s]; red[kNH + t] += red[kNH + t + s]; }
    __syncthreads();
  }
  if (t == 0) {
    float z0 = red[0] + b2[0], z1 = red[kNH] + b2[1];
    float m = fmaxf(z0, z1);
    float lse = m + logf(__expf(z0 - m) + __expf(z1 - m));
    out[b * 2 + 0] = z0 - lse;
    out[b * 2 + 1] = z1 - lse;
  }
}

}  // namespace

extern "C" void kernel_launch(void* const* d_in, const int* in_sizes, int n_in,
                              void* d_out, int out_size, void* d_ws, size_t ws_size,
                              hipStream_t stream) {
  const float* x     = (const float*)d_in[0];
  const int*   ei    = (const int*)d_in[1];
  const float* Wgcn  = (const float*)d_in[3];
  const float* bgcn  = (const float*)d_in[4];
  const float* l0Wih = (const float*)d_in[5];   // (2,512,768) == (1024,768) (N,K)
  const float* l0Whh = (const float*)d_in[6];
  const float* l0b   = (const float*)d_in[7];
  const float* l1Wih = (const float*)d_in[8];   // (2,512,256); bwd half at +512*256 (N,K)
  const float* l1Whh = (const float*)d_in[9];
  const float* l1b   = (const float*)d_in[10];
  const float* Wseq  = (const float*)d_in[11];
  const float* bseq  = (const float*)d_in[12];
  const float* W1    = (const float*)d_in[13];
  const float* b1    = (const float*)d_in[14];
  const float* W2    = (const float*)d_in[15];
  const float* b2    = (const float*)d_in[16];
  float* out = (float*)d_out;
  char* ws = (char*)d_ws;

  // ws layout (aliasing; peak == r0's ~168 MB):
  //   [0,134.2MB)  Z0 fp32 (lstm0 preacts); GCN phase aliases: hgcn@0(32MB),
  //                xgfull@32MB(32MB), cnt@64MB, offs@+1MB, cursor@+2MB, elist@+3MB,
  //                dinv@+6MB, gWhi/lo@75MB (dead before lstm0 gemm writes Z0);
  //                l1hi/lo@100MB (converted AFTER lstm0 rec, Z1b only uses [0,64MB))
  //   [134.2,167.8MB) Y0 fp32; l0hi/lo alias here (dead before lstm0 rec writes Y0)
  //   then xgraph (128KB), h1b (64KB)
  float* Z0     = (float*)(ws);
  float* Y0     = (float*)(ws + 134217728UL);
  float* xgraph = (float*)(ws + 134217728UL + 33554432UL);
  float* h1b    = (float*)(ws + 134217728UL + 33554432UL + 131072UL);
  float* hgcn   = Z0;
  float* xgfull = (float*)(ws + 33554432UL);
  int*   cnt    = (int*)(ws + 67108864UL);
  int*   offs   = (int*)(ws + 67108864UL + 1048576UL);
  int*   cursor = (int*)(ws + 67108864UL + 2097152UL);
  int*   elist  = (int*)(ws + 67108864UL + 3145728UL);
  float* dinv   = (float*)(ws + 67108864UL + 6291456UL);
  float* Z1b    = Z0;

  unsigned short* gWhi = (unsigned short*)(ws + 78643200UL);            // 256x768 bf16
  unsigned short* gWlo = (unsigned short*)(ws + 78643200UL + 393216UL);
  unsigned short* l0hi = (unsigned short*)(ws + 134217728UL);           // 1024x768 bf16
  unsigned short* l0lo = (unsigned short*)(ws + 134217728UL + 1572864UL);
  unsigned short* l1hi = (unsigned short*)(ws + 104857600UL);           // 512x256 bf16
  unsigned short* l1lo = (unsigned short*)(ws + 104857600UL + 262144UL);

  const int* erow = ei;
  const int* ecol = ei + kE;

  // ---- GCN path ----
  hipMemsetAsync(cnt, 0, kN * sizeof(int), stream);
  count_edges<<<kE / 256, 256, 0, stream>>>(ecol, cnt);
  scan_dinv<<<1, 1024, 0, stream>>>(cnt, offs, cursor, dinv);
  fill_csr<<<kE / 256, 256, 0, stream>>>(erow, ecol, cursor, elist);
  convert_bt<<<(kNH * kF + 255) / 256, 256, 0, stream>>>(Wgcn, gWhi, gWlo, kNH, kF, 1);
  gemm3<<<dim3(kNH / 128, kN / 128), 256, 0, stream>>>(x, gWhi, gWlo, hgcn, kN, kNH, kF);
  gcn_gather<<<kN, 256, 0, stream>>>(hgcn, offs, elist, dinv, bgcn, xgfull);
  segmax<<<kB, 256, 0, stream>>>(xgfull, xgraph);

  // ---- LSTM path ----
  convert_bt<<<(1024 * kF + 255) / 256, 256, 0, stream>>>(l0Wih, l0hi, l0lo, 1024, kF, 0);
  gemm3<<<dim3(1024 / 128, kN / 128), 256, 0, stream>>>(x, l0hi, l0lo, Z0, kN, 1024, kF);
  lstm_rec<<<256, 512, 0, stream>>>(Z0, 1024, l0Whh, l0b, Y0, nullptr, 0);
  convert_bt<<<(512 * kNH + 255) / 256, 256, 0, stream>>>(l1Wih + 512 * 256, l1hi, l1lo,
                                                          512, kNH, 0);
  gemm3<<<dim3(512 / 128, kN / 128), 256, 0, stream>>>(Y0, l1hi, l1lo, Z1b, kN, 512, kNH);
  lstm_rec<<<128, 512, 0, stream>>>(Z1b, 512, l1Whh, l1b, nullptr, h1b, 1);

  // ---- head ----
  head<<<kB, 256, 0, stream>>>(Y0, h1b, l1Wih, l1b, xgraph, Wseq, bseq, W1, b1, W2, b2, out);
}

// Round 3
// 1094.116 us; speedup vs baseline: 1.6479x; 1.0285x over previous
//
#include <hip/hip_runtime.h>
#include <math.h>

// Model_13486197309850: GCN(+self-loop sym-norm, segment_max) || 2-layer BiLSTM -> MLP head.
// R2->R3: lstm_rec rewritten with quad k-split:
//   thread (j = t>>2, ks = t&3) computes all 4 gates of h-unit j over k-slice [32ks,32ks+32),
//   weights pinned in VGPRs via asm (defeats the remat-into-loop that made r2 show VGPR=80),
//   LDS h-traffic cut 4x, partials combined via 2x shfl_xor in-quad, 1 barrier/step
//   (double-buffered hbuf), gbuf eliminated.
// GEMMs (bf16 MFMA 3-term hi/lo split) unchanged from r2.

namespace {

constexpr int kN  = 32768;
constexpr int kB  = 128;
constexpr int kL  = 256;
constexpr int kF  = 768;
constexpr int kNH = 256;
constexpr int kH  = 128;
constexpr int kE  = 524288;

typedef __attribute__((ext_vector_type(8))) short bf16x8;
typedef __attribute__((ext_vector_type(4))) float f32x4;
typedef __attribute__((address_space(3))) unsigned int lds_u32;
typedef __attribute__((address_space(1))) unsigned int glb_u32;

__device__ __forceinline__ float sigf(float x)  { return 1.f / (1.f + __expf(-x)); }
__device__ __forceinline__ float tanh_f(float x){ return 1.f - 2.f / (1.f + __expf(2.f * x)); }

__device__ __forceinline__ unsigned short f2bf(float f) {
  unsigned int u = __float_as_uint(f);
  u = u + 0x7fffu + ((u >> 16) & 1u);   // RNE to bf16
  return (unsigned short)(u >> 16);
}
__device__ __forceinline__ float bf2f(unsigned short h) {
  return __uint_as_float((unsigned int)h << 16);
}

// ---------------- GCN: degree count / scan / CSR fill ----------------

__global__ void count_edges(const int* __restrict__ col, int* __restrict__ cnt) {
  int e = blockIdx.x * 256 + threadIdx.x;
  if (e < kE) atomicAdd(&cnt[col[e]], 1);
}

__global__ void scan_dinv(const int* __restrict__ cnt, int* __restrict__ offs,
                          int* __restrict__ cursor, float* __restrict__ dinv) {
  __shared__ int part[1024];
  int t = threadIdx.x;
  int base = t * 32;
  int loc[32];
  int s = 0;
#pragma unroll
  for (int i = 0; i < 32; i++) { loc[i] = cnt[base + i]; s += loc[i]; }
  part[t] = s;
  __syncthreads();
  for (int d = 1; d < 1024; d <<= 1) {
    int v = part[t];
    int add = (t >= d) ? part[t - d] : 0;
    __syncthreads();
    part[t] = v + add;
    __syncthreads();
  }
  int run = (t == 0) ? 0 : part[t - 1];
#pragma unroll
  for (int i = 0; i < 32; i++) {
    offs[base + i] = run;
    cursor[base + i] = run;
    dinv[base + i] = rsqrtf((float)(loc[i] + 1));
    run += loc[i];
  }
  if (t == 1023) offs[kN] = run;
}

__global__ void fill_csr(const int* __restrict__ row, const int* __restrict__ col,
                         int* __restrict__ cursor, int* __restrict__ elist) {
  int e = blockIdx.x * 256 + threadIdx.x;
  if (e < kE) {
    int c = col[e];
    int p = atomicAdd(&cursor[c], 1);
    elist[p] = row[e];
  }
}

// ---------------- weight conversion: fp32 -> (N,K) bf16 hi/lo ----------------

__global__ void convert_bt(const float* __restrict__ W, unsigned short* __restrict__ hi,
                           unsigned short* __restrict__ lo, int Nn, int Kk, int trans) {
  int idx = blockIdx.x * 256 + threadIdx.x;
  if (idx >= Nn * Kk) return;
  int n = idx / Kk, k = idx - n * Kk;
  float f = trans ? W[(size_t)k * Nn + n] : W[idx];
  unsigned short h = f2bf(f);
  hi[idx] = h;
  lo[idx] = f2bf(f - bf2f(h));
}

// ---------------- MFMA GEMM, 3-term hi/lo split (unchanged from r2) ----------------

__global__ __launch_bounds__(256, 2) void gemm3(const float* __restrict__ A,
                                                const unsigned short* __restrict__ Bhi,
                                                const unsigned short* __restrict__ Blo,
                                                float* __restrict__ C,
                                                int M, int N, int K) {
  __shared__ __align__(16) char lds[32768];
  const int tid = threadIdx.x;
  const int lane = tid & 63;
  const int w = tid >> 6, wr = w >> 1, wc = w & 1;
  const int m0 = blockIdx.y * 128, n0 = blockIdx.x * 128;

  f32x4 acc[4][4];
#pragma unroll
  for (int i = 0; i < 4; i++)
#pragma unroll
    for (int j = 0; j < 4; j++) acc[i][j] = (f32x4)0.f;

  const float* aptr[4];
  int aoff[4];
#pragma unroll
  for (int i = 0; i < 4; i++) {
    int f = tid + i * 256;
    int row = f >> 3, kq4 = f & 7;
    aptr[i] = A + (size_t)(m0 + row) * K + kq4 * 4;
    int sub = row >> 4, r = row & 15, q = kq4 >> 1, hs = kq4 & 1;
    aoff[i] = sub * 1024 + (q * 16 + r) * 16 + hs * 8;
  }
  const unsigned short* bsrc[4];
  int boff[4];
#pragma unroll
  for (int j = 0; j < 4; j++) {
    int id = w * 4 + j;
    int isLo = id >> 3, sub = id & 7;
    const unsigned short* Bp = isLo ? Blo : Bhi;
    bsrc[j] = Bp + (size_t)(n0 + sub * 16 + (lane & 15)) * K + (lane >> 4) * 8;
    boff[j] = 16384 + isLo * 8192 + sub * 1024;
  }

  for (int k0 = 0; k0 < K; k0 += 32) {
#pragma unroll
    for (int j = 0; j < 4; j++) {
      __builtin_amdgcn_global_load_lds((const glb_u32*)bsrc[j],
                                       (lds_u32*)(lds + boff[j]), 16, 0, 0);
      bsrc[j] += 32;
    }
#pragma unroll
    for (int i = 0; i < 4; i++) {
      f32x4 v = *(const f32x4*)(aptr[i]);
      aptr[i] += 32;
      unsigned short h0 = f2bf(v.x), h1 = f2bf(v.y), h2 = f2bf(v.z), h3 = f2bf(v.w);
      unsigned short g0 = f2bf(v.x - bf2f(h0)), g1 = f2bf(v.y - bf2f(h1));
      unsigned short g2 = f2bf(v.z - bf2f(h2)), g3 = f2bf(v.w - bf2f(h3));
      uint2 hv, lv;
      hv.x = (unsigned int)h0 | ((unsigned int)h1 << 16);
      hv.y = (unsigned int)h2 | ((unsigned int)h3 << 16);
      lv.x = (unsigned int)g0 | ((unsigned int)g1 << 16);
      lv.y = (unsigned int)g2 | ((unsigned int)g3 << 16);
      *(uint2*)(lds + aoff[i]) = hv;
      *(uint2*)(lds + aoff[i] + 8192) = lv;
    }
    __syncthreads();

    const bf16x8* L = (const bf16x8*)lds;
    bf16x8 ah[4], al[4], bh[4], bl[4];
#pragma unroll
    for (int m = 0; m < 4; m++) {
      ah[m] = L[(wr * 4 + m) * 64 + lane];
      al[m] = L[512 + (wr * 4 + m) * 64 + lane];
    }
#pragma unroll
    for (int n = 0; n < 4; n++) {
      bh[n] = L[1024 + (wc * 4 + n) * 64 + lane];
      bl[n] = L[1536 + (wc * 4 + n) * 64 + lane];
    }
#pragma unroll
    for (int m = 0; m < 4; m++)
#pragma unroll
      for (int n = 0; n < 4; n++) {
        acc[m][n] = __builtin_amdgcn_mfma_f32_16x16x32_bf16(ah[m], bh[n], acc[m][n], 0, 0, 0);
        acc[m][n] = __builtin_amdgcn_mfma_f32_16x16x32_bf16(ah[m], bl[n], acc[m][n], 0, 0, 0);
        acc[m][n] = __builtin_amdgcn_mfma_f32_16x16x32_bf16(al[m], bh[n], acc[m][n], 0, 0, 0);
      }
    __syncthreads();
  }

#pragma unroll
  for (int m = 0; m < 4; m++)
#pragma unroll
    for (int n = 0; n < 4; n++) {
      int r0 = m0 + wr * 64 + m * 16 + (lane >> 4) * 4;
      int cc = n0 + wc * 64 + n * 16 + (lane & 15);
#pragma unroll
      for (int j = 0; j < 4; j++)
        C[(size_t)(r0 + j) * N + cc] = acc[m][n][j];
    }
}

// ---------------- GCN gather + relu(+bias), then segment max ----------------

__global__ __launch_bounds__(256) void gcn_gather(const float* __restrict__ hg,
                                                  const int* __restrict__ offs,
                                                  const int* __restrict__ elist,
                                                  const float* __restrict__ dinv,
                                                  const float* __restrict__ bgcn,
                                                  float* __restrict__ out) {
  int n = blockIdx.x, j = threadIdx.x;
  float di = dinv[n];
  float acc = hg[(size_t)n * kNH + j] * (di * di);
  int s = offs[n], e = offs[n + 1];
  int p = s;
  for (; p + 4 <= e; p += 4) {
    int r0 = elist[p], r1 = elist[p + 1], r2 = elist[p + 2], r3 = elist[p + 3];
    float w0 = di * dinv[r0], w1 = di * dinv[r1], w2 = di * dinv[r2], w3 = di * dinv[r3];
    float v0 = hg[(size_t)r0 * kNH + j], v1 = hg[(size_t)r1 * kNH + j];
    float v2 = hg[(size_t)r2 * kNH + j], v3 = hg[(size_t)r3 * kNH + j];
    acc = fmaf(v0, w0, acc); acc = fmaf(v1, w1, acc);
    acc = fmaf(v2, w2, acc); acc = fmaf(v3, w3, acc);
  }
  for (; p < e; p++) {
    int r = elist[p];
    acc = fmaf(hg[(size_t)r * kNH + j], di * dinv[r], acc);
  }
  acc += bgcn[j];
  out[(size_t)n * kNH + j] = fmaxf(acc, 0.f);
}

__global__ __launch_bounds__(256) void segmax(const float* __restrict__ xg_full,
                                              float* __restrict__ x_graph) {
  int g = blockIdx.x, j = threadIdx.x;
  const float* base = xg_full + (size_t)g * kL * kNH + j;
  float m0 = -1e30f, m1 = -1e30f, m2 = -1e30f, m3 = -1e30f;
  for (int t = 0; t < kL; t += 4) {
    m0 = fmaxf(m0, base[(size_t)(t + 0) * kNH]);
    m1 = fmaxf(m1, base[(size_t)(t + 1) * kNH]);
    m2 = fmaxf(m2, base[(size_t)(t + 2) * kNH]);
    m3 = fmaxf(m3, base[(size_t)(t + 3) * kNH]);
  }
  x_graph[g * kNH + j] = fmaxf(fmaxf(m0, m1), fmaxf(m2, m3));
}

// ---------------- LSTM recurrence: quad k-split ----------------
// 512 threads: j = t>>2 (h-unit), ks = t&3 (k-slice of 32).
// Thread holds w[4][32] (gates i,f,g,o of unit j, k in [32ks,32ks+32)) in VGPRs
// (asm-pinned). Per step: read 32 h from LDS, 4x32 FMA, fold z+bias (owning lane),
// 2x shfl_xor quad-allreduce, gates+state redundantly per quad, ks==0 writes h.
// Double-buffered hbuf -> 1 barrier/step.
__global__ __launch_bounds__(512, 2) void lstm_rec(const float* __restrict__ Z, int zstride,
                                                   const float* __restrict__ Whh2,
                                                   const float* __restrict__ bias2,
                                                   float* __restrict__ Y0,
                                                   float* __restrict__ hfin, int mode) {
  __shared__ __align__(16) float hbuf[2][kH];
  int b, dir;
  if (mode == 0) { dir = blockIdx.x >> 7; b = blockIdx.x & 127; }
  else           { dir = 1;               b = blockIdx.x; }
  const bool rev = (dir == 1);
  const int t0 = threadIdx.x;
  const int j = t0 >> 2;
  const int ks = t0 & 3;

  float w[4][32];
  {
    const float* wb = Whh2 + (size_t)dir * 512 * kH + (size_t)j * kH + ks * 32;
#pragma unroll
    for (int q = 0; q < 4; q++) {
      const float* wr = wb + (size_t)q * kH * kH;  // gate q row = q*128 + j
#pragma unroll
      for (int kk = 0; kk < 8; kk++) {
        float4 v = *(const float4*)(wr + kk * 4);
        w[q][kk * 4 + 0] = v.x; w[q][kk * 4 + 1] = v.y;
        w[q][kk * 4 + 2] = v.z; w[q][kk * 4 + 3] = v.w;
      }
    }
  }
  // pin weights in VGPRs: opaque asm makes remat-into-loop impossible
#pragma unroll
  for (int q = 0; q < 4; q++)
#pragma unroll
    for (int kk = 0; kk < 32; kk++) asm volatile("" : "+v"(w[q][kk]));

  const float bg = bias2[dir * 512 + ks * kH + j];
  const int zcol = (mode == 0) ? dir * 512 : 0;
  float c = 0.f, hn = 0.f;

  if (ks == 0) hbuf[0][j] = 0.f;

  const float* zp = Z + (size_t)(b * kL + (rev ? kL - 1 : 0)) * zstride + zcol + ks * kH + j;
  const long zinc = rev ? -(long)zstride : (long)zstride;
  float zt = *zp;
  __syncthreads();

  for (int t = 0; t < kL; t++) {
    const int tt = rev ? (kL - 1 - t) : t;
    float znext = 0.f;
    if (t < kL - 1) znext = zp[zinc];
    zp += zinc;
    const int cur = t & 1;

    float h[32];
    const float4* hp = (const float4*)&hbuf[cur][ks * 32];
#pragma unroll
    for (int kk = 0; kk < 8; kk++) {
      float4 v = hp[kk];
      h[kk * 4 + 0] = v.x; h[kk * 4 + 1] = v.y; h[kk * 4 + 2] = v.z; h[kk * 4 + 3] = v.w;
    }

    float a0 = 0.f, a1 = 0.f, a2 = 0.f, a3 = 0.f;
#pragma unroll
    for (int kk = 0; kk < 32; kk++) {
      a0 = fmaf(w[0][kk], h[kk], a0);
      a1 = fmaf(w[1][kk], h[kk], a1);
      a2 = fmaf(w[2][kk], h[kk], a2);
      a3 = fmaf(w[3][kk], h[kk], a3);
    }
    const float zb = zt + bg;
    a0 += (ks == 0) ? zb : 0.f;
    a1 += (ks == 1) ? zb : 0.f;
    a2 += (ks == 2) ? zb : 0.f;
    a3 += (ks == 3) ? zb : 0.f;
    a0 += __shfl_xor(a0, 1); a1 += __shfl_xor(a1, 1);
    a2 += __shfl_xor(a2, 1); a3 += __shfl_xor(a3, 1);
    a0 += __shfl_xor(a0, 2); a1 += __shfl_xor(a1, 2);
    a2 += __shfl_xor(a2, 2); a3 += __shfl_xor(a3, 2);

    const float ig = sigf(a0), fg = sigf(a1), gg = tanh_f(a2), og = sigf(a3);
    c = fg * c + ig * gg;
    hn = og * tanh_f(c);
    if (ks == 0) {
      hbuf[cur ^ 1][j] = hn;
      if (mode == 0) Y0[(size_t)(b * kL + tt) * kNH + dir * kH + j] = hn;
    }
    __syncthreads();
    zt = znext;
  }
  if (mode == 1 && ks == 0) hfin[b * kH + j] = hn;
}

// ---------------- head (unchanged) ----------------

__global__ __launch_bounds__(256) void head(const float* __restrict__ Y0,
                                            const float* __restrict__ h1b,
                                            const float* __restrict__ Wih1f,
                                            const float* __restrict__ b1f,
                                            const float* __restrict__ xgraph,
                                            const float* __restrict__ Wseq,
                                            const float* __restrict__ bseq,
                                            const float* __restrict__ W1,
                                            const float* __restrict__ b1,
                                            const float* __restrict__ W2,
                                            const float* __restrict__ b2,
                                            float* __restrict__ out) {
  int b = blockIdx.x, t = threadIdx.x;
  __shared__ __align__(16) float x0[kNH];
  __shared__ float gl[512];
  __shared__ __align__(16) float seq[kNH];
  __shared__ __align__(16) float v[512];
  __shared__ __align__(16) float o1[kNH];
  __shared__ float red[512];

  x0[t] = Y0[(size_t)(b * kL) * kNH + t];
  if (t >= kH) seq[t] = h1b[b * kH + (t - kH)];
  __syncthreads();

#pragma unroll
  for (int half = 0; half < 2; half++) {
    int g = t + half * 256;
    const float* wr = Wih1f + (size_t)g * kNH;
    float acc = b1f[g];
#pragma unroll 8
    for (int k = 0; k < kNH; k += 4) {
      float4 xv = *(const float4*)&x0[k];
      float4 wv = *(const float4*)(wr + k);
      acc = fmaf(xv.x, wv.x, acc); acc = fmaf(xv.y, wv.y, acc);
      acc = fmaf(xv.z, wv.z, acc); acc = fmaf(xv.w, wv.w, acc);
    }
    gl[g] = acc;
  }
  __syncthreads();
  if (t < kH) {
    float ig = sigf(gl[t]);
    float gg = tanh_f(gl[2 * kH + t]);
    float og = sigf(gl[3 * kH + t]);
    float c = ig * gg;
    seq[t] = og * tanh_f(c);
  }
  v[t] = xgraph[b * kNH + t];
  __syncthreads();

  {
    float acc = bseq[t];
#pragma unroll 4
    for (int k = 0; k < kNH; k++) acc = fmaf(seq[k], Wseq[(size_t)k * kNH + t], acc);
    v[kNH + t] = (acc > 0.f) ? acc : 0.01f * acc;
  }
  __syncthreads();

  {
    float acc = b1[t];
#pragma unroll 4
    for (int k = 0; k < 512; k++) acc = fmaf(v[k], W1[(size_t)k * kNH + t], acc);
    o1[t] = fmaxf(acc, 0.f);
  }
  __syncthreads();

  red[t]       = o1[t] * W2[t * 2 + 0];
  red[kNH + t] = o1[t] * W2[t * 2 + 1];
  __syncthreads();
  for (int s = 128; s > 0; s >>= 1) {
    if (t < s) { red[t] += red[t + s]; red[kNH + t] += red[kNH + t + s]; }
    __syncthreads();
  }
  if (t == 0) {
    float z0 = red[0] + b2[0], z1 = red[kNH] + b2[1];
    float m = fmaxf(z0, z1);
    float lse = m + logf(__expf(z0 - m) + __expf(z1 - m));
    out[b * 2 + 0] = z0 - lse;
    out[b * 2 + 1] = z1 - lse;
  }
}

}  // namespace

extern "C" void kernel_launch(void* const* d_in, const int* in_sizes, int n_in,
                              void* d_out, int out_size, void* d_ws, size_t ws_size,
                              hipStream_t stream) {
  const float* x     = (const float*)d_in[0];
  const int*   ei    = (const int*)d_in[1];
  const float* Wgcn  = (const float*)d_in[3];
  const float* bgcn  = (const float*)d_in[4];
  const float* l0Wih = (const float*)d_in[5];
  const float* l0Whh = (const float*)d_in[6];
  const float* l0b   = (const float*)d_in[7];
  const float* l1Wih = (const float*)d_in[8];
  const float* l1Whh = (const float*)d_in[9];
  const float* l1b   = (const float*)d_in[10];
  const float* Wseq  = (const float*)d_in[11];
  const float* bseq  = (const float*)d_in[12];
  const float* W1    = (const float*)d_in[13];
  const float* b1    = (const float*)d_in[14];
  const float* W2    = (const float*)d_in[15];
  const float* b2    = (const float*)d_in[16];
  float* out = (float*)d_out;
  char* ws = (char*)d_ws;

  float* Z0     = (float*)(ws);
  float* Y0     = (float*)(ws + 134217728UL);
  float* xgraph = (float*)(ws + 134217728UL + 33554432UL);
  float* h1b    = (float*)(ws + 134217728UL + 33554432UL + 131072UL);
  float* hgcn   = Z0;
  float* xgfull = (float*)(ws + 33554432UL);
  int*   cnt    = (int*)(ws + 67108864UL);
  int*   offs   = (int*)(ws + 67108864UL + 1048576UL);
  int*   cursor = (int*)(ws + 67108864UL + 2097152UL);
  int*   elist  = (int*)(ws + 67108864UL + 3145728UL);
  float* dinv   = (float*)(ws + 67108864UL + 6291456UL);
  float* Z1b    = Z0;

  unsigned short* gWhi = (unsigned short*)(ws + 78643200UL);
  unsigned short* gWlo = (unsigned short*)(ws + 78643200UL + 393216UL);
  unsigned short* l0hi = (unsigned short*)(ws + 134217728UL);
  unsigned short* l0lo = (unsigned short*)(ws + 134217728UL + 1572864UL);
  unsigned short* l1hi = (unsigned short*)(ws + 104857600UL);
  unsigned short* l1lo = (unsigned short*)(ws + 104857600UL + 262144UL);

  const int* erow = ei;
  const int* ecol = ei + kE;

  // ---- GCN path ----
  hipMemsetAsync(cnt, 0, kN * sizeof(int), stream);
  count_edges<<<kE / 256, 256, 0, stream>>>(ecol, cnt);
  scan_dinv<<<1, 1024, 0, stream>>>(cnt, offs, cursor, dinv);
  fill_csr<<<kE / 256, 256, 0, stream>>>(erow, ecol, cursor, elist);
  convert_bt<<<(kNH * kF + 255) / 256, 256, 0, stream>>>(Wgcn, gWhi, gWlo, kNH, kF, 1);
  gemm3<<<dim3(kNH / 128, kN / 128), 256, 0, stream>>>(x, gWhi, gWlo, hgcn, kN, kNH, kF);
  gcn_gather<<<kN, 256, 0, stream>>>(hgcn, offs, elist, dinv, bgcn, xgfull);
  segmax<<<kB, 256, 0, stream>>>(xgfull, xgraph);

  // ---- LSTM path ----
  convert_bt<<<(1024 * kF + 255) / 256, 256, 0, stream>>>(l0Wih, l0hi, l0lo, 1024, kF, 0);
  gemm3<<<dim3(1024 / 128, kN / 128), 256, 0, stream>>>(x, l0hi, l0lo, Z0, kN, 1024, kF);
  lstm_rec<<<256, 512, 0, stream>>>(Z0, 1024, l0Whh, l0b, Y0, nullptr, 0);
  convert_bt<<<(512 * kNH + 255) / 256, 256, 0, stream>>>(l1Wih + 512 * 256, l1hi, l1lo,
                                                          512, kNH, 0);
  gemm3<<<dim3(512 / 128, kN / 128), 256, 0, stream>>>(Y0, l1hi, l1lo, Z1b, kN, 512, kNH);
  lstm_rec<<<128, 512, 0, stream>>>(Z1b, 512, l1Whh, l1b, nullptr, h1b, 1);

  // ---- head ----
  head<<<kB, 256, 0, stream>>>(Y0, h1b, l1Wih, l1b, xgraph, Wseq, bseq, W1, b1, W2, b2, out);
}